// Round 1
// baseline (1036.201 us; speedup 1.0000x reference)
//
#include <hip/hip_runtime.h>
#include <hip/hip_bf16.h>
#include <math.h>

// Problem constants
#define B_   64
#define L_   577
#define D_   512
#define E_   1024
#define H_   512
#define K_   288            // selected tokens per batch
#define N_   (B_ * K_)      // 18432 total rows
#define KBIG 1024           // concatenated K for fused GEMM2

// ---------------- workspace layout (bytes) ----------------
// wbig    : 1024*1024 f32  = 4,194,304
// biasbig : 1024 f32       = 4,096
// musig   : 1024 f32       = 4,096   (mu[512], rsig[512])
// idx     : 18432 i32      = 73,728
// partial : 2*128*512 f32  = 524,288
// Abig    : 18432*1024 f32 = 75,497,472   (cols 0..511 feats, 512..1023 h/hbn)
// local   : 18432*1024 f32 = 75,497,472
#define OFF_WBIG    0
#define OFF_BIASBIG (4194304)
#define OFF_MUSIG   (4194304 + 4096)
#define OFF_IDX     (4194304 + 8192)
#define OFF_PART    (4194304 + 8192 + 73728 + 256)   // pad to keep alignment
#define OFF_ABIG    (OFF_PART + 524288)
#define OFF_LOCAL   (OFF_ABIG + (size_t)N_ * 1024 * 4)

// ---------------- kernel 1: pack Wbig = [fc_w | mlp_w1], biasbig = fc_b + b1
__global__ __launch_bounds__(256) void prep_kernel(
    const float* __restrict__ fc_w, const float* __restrict__ fc_b,
    const float* __restrict__ w1,   const float* __restrict__ b1,
    float* __restrict__ wbig, float* __restrict__ biasbig) {
  int gid = blockIdx.x * 256 + threadIdx.x;      // 262144 float4s
  int e  = gid >> 8;                             // 1024 rows
  int c4 = gid & 255;                            // 256 float4 per row
  float4 v;
  if (c4 < 128) v = ((const float4*)(fc_w + e * D_))[c4];
  else          v = ((const float4*)(w1   + e * H_))[c4 - 128];
  ((float4*)wbig)[gid] = v;
  if (gid < E_) biasbig[gid] = fc_b[gid] + b1[gid];
}

// ---------------- kernel 2: stable top-k per batch via rank
__global__ __launch_bounds__(256) void topk_kernel(
    const float* __restrict__ atten, int* __restrict__ idx) {
  __shared__ float s[L_];
  int b = blockIdx.x;
  const float* row = atten + (size_t)b * L_ * L_;   // atten[b][0][:]
  for (int i = threadIdx.x; i < L_; i += 256) s[i] = (i == 0) ? -1.0f : row[i];
  __syncthreads();
  for (int i = threadIdx.x; i < L_; i += 256) {
    float si = s[i];
    int rank = 0;
    for (int j = 0; j < L_; ++j) {
      float sj = s[j];
      rank += (sj > si) || (sj == si && j < i);
    }
    if (rank < K_) idx[b * K_ + rank] = i;
  }
}

// ---------------- kernel 3: gather selected rows + L2 normalize -> Abig[:,0:512]
__global__ __launch_bounds__(128) void gather_norm_kernel(
    const float* __restrict__ base, const int* __restrict__ idx,
    float* __restrict__ abig) {
  int r = blockIdx.x;            // 0..N_-1
  int b = r / K_;
  int tok = idx[r];
  const float* src = base + ((size_t)b * L_ + tok) * D_;
  float4 v = ((const float4*)src)[threadIdx.x];     // 128 thr * 4 = 512
  float ss = v.x * v.x + v.y * v.y + v.z * v.z + v.w * v.w;
  #pragma unroll
  for (int o = 32; o > 0; o >>= 1) ss += __shfl_down(ss, o, 64);
  __shared__ float wsum[2];
  if ((threadIdx.x & 63) == 0) wsum[threadIdx.x >> 6] = ss;
  __syncthreads();
  float total = wsum[0] + wsum[1];
  float inv = 1.0f / (sqrtf(total) + 1e-8f);
  float4 o4 = make_float4(v.x * inv, v.y * inv, v.z * inv, v.w * inv);
  ((float4*)(abig + (size_t)r * KBIG))[threadIdx.x] = o4;
}

// ---------------- generic fp32 tiled GEMM: C[m,n] = A[m,:K] . W[n,:K] + bias[n]
// A row-major lda, W row-major [N][K] ldw, C row-major ldc. Tiles 64x64x16.
__global__ __launch_bounds__(256) void gemm_bias_kernel(
    const float* __restrict__ A, int lda,
    const float* __restrict__ W, int ldw,
    const float* __restrict__ bias,
    float* __restrict__ C, int ldc, int K) {
  __shared__ float As[16][64];
  __shared__ float Bs[16][64];
  int tid = threadIdx.x;
  int m0 = blockIdx.x * 64;
  int n0 = blockIdx.y * 64;
  int tm = (tid & 15) * 4;
  int tn = (tid >> 4) * 4;
  float acc[4][4] = {{0.f}};
  int lr = tid >> 2;            // 0..63
  int lk = (tid & 3) * 4;       // 0,4,8,12
  const float* aptr = A + (size_t)(m0 + lr) * lda + lk;
  const float* wptr = W + (size_t)(n0 + lr) * ldw + lk;
  for (int k0 = 0; k0 < K; k0 += 16) {
    float4 av = *(const float4*)(aptr + k0);
    float4 wv = *(const float4*)(wptr + k0);
    __syncthreads();
    As[lk + 0][lr] = av.x; As[lk + 1][lr] = av.y;
    As[lk + 2][lr] = av.z; As[lk + 3][lr] = av.w;
    Bs[lk + 0][lr] = wv.x; Bs[lk + 1][lr] = wv.y;
    Bs[lk + 2][lr] = wv.z; Bs[lk + 3][lr] = wv.w;
    __syncthreads();
    #pragma unroll
    for (int kk = 0; kk < 16; ++kk) {
      float4 a = *(const float4*)&As[kk][tm];
      float4 bv = *(const float4*)&Bs[kk][tn];
      acc[0][0] += a.x * bv.x; acc[0][1] += a.x * bv.y;
      acc[0][2] += a.x * bv.z; acc[0][3] += a.x * bv.w;
      acc[1][0] += a.y * bv.x; acc[1][1] += a.y * bv.y;
      acc[1][2] += a.y * bv.z; acc[1][3] += a.y * bv.w;
      acc[2][0] += a.z * bv.x; acc[2][1] += a.z * bv.y;
      acc[2][2] += a.z * bv.z; acc[2][3] += a.z * bv.w;
      acc[3][0] += a.w * bv.x; acc[3][1] += a.w * bv.y;
      acc[3][2] += a.w * bv.z; acc[3][3] += a.w * bv.w;
    }
  }
  float4 bb = *(const float4*)(bias + n0 + tn);
  #pragma unroll
  for (int mi = 0; mi < 4; ++mi) {
    float4 o = make_float4(acc[mi][0] + bb.x, acc[mi][1] + bb.y,
                           acc[mi][2] + bb.z, acc[mi][3] + bb.w);
    *(float4*)(C + (size_t)(m0 + tm + mi) * ldc + n0 + tn) = o;
  }
}

// ---------------- kernel 5: BN stats stage A (partial sums per 144-row chunk)
__global__ __launch_bounds__(256) void bn_stats1_kernel(
    const float* __restrict__ h, float* __restrict__ partial) {
  int blk = blockIdx.x;          // 128 blocks
  int t = threadIdx.x;
  int r0 = blk * 144;
  float s0 = 0.f, q0 = 0.f, s1 = 0.f, q1 = 0.f;
  for (int i = 0; i < 144; ++i) {
    const float* row = h + (size_t)(r0 + i) * KBIG;
    float a = row[t], b2 = row[t + 256];
    s0 += a; q0 += a * a; s1 += b2; q1 += b2 * b2;
  }
  partial[blk * 512 + t] = s0;
  partial[blk * 512 + t + 256] = s1;
  partial[65536 + blk * 512 + t] = q0;
  partial[65536 + blk * 512 + t + 256] = q1;
}

// ---------------- kernel 6: BN stats stage B -> mu, rsig
__global__ __launch_bounds__(256) void bn_stats2_kernel(
    const float* __restrict__ partial, float* __restrict__ musig) {
  int c = blockIdx.x * 256 + threadIdx.x;    // 512 threads
  float S = 0.f, Q = 0.f;
  for (int i = 0; i < 128; ++i) {
    S += partial[i * 512 + c];
    Q += partial[65536 + i * 512 + c];
  }
  const float invN = 1.0f / (float)N_;
  float mu = S * invN;
  float var = Q * invN - mu * mu;
  musig[c] = mu;
  musig[512 + c] = rsqrtf(var + 1e-5f);
}

// ---------------- kernel 7: BN apply + ReLU in place on Abig[:,512:1024]
__global__ __launch_bounds__(256) void bn_apply_kernel(
    float* __restrict__ abig, const float* __restrict__ musig,
    const float* __restrict__ gamma, const float* __restrict__ beta) {
  int gid = blockIdx.x * 256 + threadIdx.x;   // N_*128
  int r = gid >> 7;
  int c4 = gid & 127;
  float4* p = (float4*)(abig + (size_t)r * KBIG + H_) + c4;
  float4 v = *p;
  int c = c4 * 4;
  float vv[4] = {v.x, v.y, v.z, v.w};
  float o[4];
  #pragma unroll
  for (int j = 0; j < 4; ++j) {
    float x = (vv[j] - musig[c + j]) * musig[512 + c + j] * gamma[c + j] + beta[c + j];
    o[j] = fmaxf(x, 0.0f);
  }
  *p = make_float4(o[0], o[1], o[2], o[3]);
}

// ---------------- kernel 8: max over k rows per batch -> out [B,E]
__global__ __launch_bounds__(256) void maxk_kernel(
    const float* __restrict__ local, float* __restrict__ out) {
  int gid = blockIdx.x * 256 + threadIdx.x;   // 65536
  int b = gid >> 10, e = gid & 1023;
  const float* p = local + (size_t)b * K_ * KBIG + e;
  float m = -INFINITY;
  for (int j = 0; j < K_; ++j) m = fmaxf(m, p[(size_t)j * KBIG]);
  out[gid] = m;
}

extern "C" void kernel_launch(void* const* d_in, const int* in_sizes, int n_in,
                              void* d_out, int out_size, void* d_ws, size_t ws_size,
                              hipStream_t stream) {
  const float* base  = (const float*)d_in[0];   // [64,577,512]
  const float* atten = (const float*)d_in[1];   // [64,577,577]
  const float* fc_w  = (const float*)d_in[2];   // [1024,512]
  const float* fc_b  = (const float*)d_in[3];   // [1024]
  const float* w0    = (const float*)d_in[4];   // [512,512]
  const float* b0    = (const float*)d_in[5];   // [512]
  const float* gamma = (const float*)d_in[6];   // [512]
  const float* beta  = (const float*)d_in[7];   // [512]
  const float* w1    = (const float*)d_in[8];   // [1024,512]
  const float* b1    = (const float*)d_in[9];   // [1024]
  float* out = (float*)d_out;

  char* ws = (char*)d_ws;
  float* wbig    = (float*)(ws + OFF_WBIG);
  float* biasbig = (float*)(ws + OFF_BIASBIG);
  float* musig   = (float*)(ws + OFF_MUSIG);
  int*   idx     = (int*)  (ws + OFF_IDX);
  float* partial = (float*)(ws + OFF_PART);
  float* abig    = (float*)(ws + OFF_ABIG);
  float* local   = (float*)(ws + OFF_LOCAL);

  // 1. pack fused weight/bias
  prep_kernel<<<1024, 256, 0, stream>>>(fc_w, fc_b, w1, b1, wbig, biasbig);
  // 2. top-k selection
  topk_kernel<<<B_, 256, 0, stream>>>(atten, idx);
  // 3. gather + l2norm -> Abig[:,0:512]
  gather_norm_kernel<<<N_, 128, 0, stream>>>(base, idx, abig);
  // 4. GEMM1: h = feats @ w0^T + b0 -> Abig[:,512:1024]
  {
    dim3 grid(N_ / 64, H_ / 64);
    gemm_bias_kernel<<<grid, 256, 0, stream>>>(abig, KBIG, w0, D_, b0,
                                               abig + H_, KBIG, D_);
  }
  // 5-6. BN stats
  bn_stats1_kernel<<<128, 256, 0, stream>>>(abig + H_, partial);
  bn_stats2_kernel<<<2, 256, 0, stream>>>(partial, musig);
  // 7. BN apply + ReLU (in place)
  bn_apply_kernel<<<(N_ * 128) / 256, 256, 0, stream>>>(abig, musig, gamma, beta);
  // 8. fused GEMM2: local = [feats|hbn] @ [fc_w|w1]^T + (fc_b+b1)
  {
    dim3 grid(N_ / 64, E_ / 64);
    gemm_bias_kernel<<<grid, 256, 0, stream>>>(abig, KBIG, wbig, KBIG, biasbig,
                                               local, KBIG, KBIG);
  }
  // 9. max over k per batch
  maxk_kernel<<<(B_ * E_) / 256, 256, 0, stream>>>(local, out);
}

// Round 3
// 355.928 us; speedup vs baseline: 2.9113x; 2.9113x over previous
//
#include <hip/hip_runtime.h>
#include <math.h>

// Problem constants
#define B_   64
#define L_   577
#define D_   512
#define E_   1024
#define H_   512
#define K_   288            // selected tokens per batch
#define N_   (B_ * K_)      // 18432 total rows
#define KBIG 1024           // concatenated K for fused GEMM2

typedef __attribute__((ext_vector_type(8))) __bf16 bf16x8;
typedef __attribute__((ext_vector_type(4))) float f32x4;
typedef __attribute__((ext_vector_type(4))) unsigned short ushort4v;

// ---------------- workspace layout (bytes) ----------------
#define OFF_WBIG    0                          // 1024*1024 bf16 = 2,097,152
#define OFF_W0B     (2097152)                  // 512*512 bf16   =   524,288
#define OFF_BIASBIG (2097152 + 524288)         // 1024 f32
#define OFF_MUSIG   (OFF_BIASBIG + 4096)       // 1024 f32 (mu, rsig)
#define OFF_IDX     (OFF_MUSIG + 4096)         // 18432 i32 = 73,728
#define OFF_PART    (OFF_IDX + 73728)          // 2*128*512 f32 = 524,288
#define OFF_ABIG    (OFF_PART + 524288)        // N*1024 bf16 = 37,748,736
#define OFF_H       (OFF_ABIG + (size_t)N_ * KBIG * 2)   // N*512 f32 = 37,748,736
#define OFF_LOCAL   (OFF_H + (size_t)N_ * H_ * 4)        // N*1024 f32 = 75,497,472

static __device__ __forceinline__ unsigned short f2bf(float f) {
  unsigned int u = __builtin_bit_cast(unsigned int, f);
  u = (u + 0x7fffu + ((u >> 16) & 1u)) >> 16;
  return (unsigned short)u;
}

#define GLOAD_LDS16(g, l)                                          \
  __builtin_amdgcn_global_load_lds(                                \
      (const __attribute__((address_space(1))) void*)(g),          \
      (__attribute__((address_space(3))) void*)(l), 16, 0, 0)

// ---------------- kernel 1: pack Wbig(bf16) = [fc_w | mlp_w1], biasbig = fc_b+b1,
//                  and W0(bf16)
__global__ __launch_bounds__(256) void prep_kernel(
    const float* __restrict__ fc_w, const float* __restrict__ fc_b,
    const float* __restrict__ w0,   const float* __restrict__ w1,
    const float* __restrict__ b1,
    unsigned short* __restrict__ wbig, unsigned short* __restrict__ w0b,
    float* __restrict__ biasbig) {
  int gid = blockIdx.x * 256 + threadIdx.x;      // 327680 total
  if (gid < 262144) {                            // wbig: 1024 rows x 256 float4-cols
    int e  = gid >> 8;
    int c4 = gid & 255;
    float4 v;
    if (c4 < 128) v = ((const float4*)(fc_w + e * D_))[c4];
    else          v = ((const float4*)(w1   + e * H_))[c4 - 128];
    ushort4v o = { f2bf(v.x), f2bf(v.y), f2bf(v.z), f2bf(v.w) };
    ((ushort4v*)wbig)[gid] = o;
    if (gid < E_) biasbig[gid] = fc_b[gid] + b1[gid];
  } else {                                       // w0b: 512x512
    int idx = gid - 262144;                      // 65536
    float4 v = ((const float4*)w0)[idx];
    ushort4v o = { f2bf(v.x), f2bf(v.y), f2bf(v.z), f2bf(v.w) };
    ((ushort4v*)w0b)[idx] = o;
  }
}

// ---------------- kernel 2: stable top-k per batch via rank
__global__ __launch_bounds__(256) void topk_kernel(
    const float* __restrict__ atten, int* __restrict__ idx) {
  __shared__ float s[L_];
  int b = blockIdx.x;
  const float* row = atten + (size_t)b * L_ * L_;   // atten[b][0][:]
  for (int i = threadIdx.x; i < L_; i += 256) s[i] = (i == 0) ? -1.0f : row[i];
  __syncthreads();
  for (int i = threadIdx.x; i < L_; i += 256) {
    float si = s[i];
    int rank = 0;
    for (int j = 0; j < L_; ++j) {
      float sj = s[j];
      rank += (sj > si) || (sj == si && j < i);
    }
    if (rank < K_) idx[b * K_ + rank] = i;
  }
}

// ---------------- kernel 3: gather + L2 normalize -> Abig[:,0:512] (bf16)
__global__ __launch_bounds__(128) void gather_norm_kernel(
    const float* __restrict__ base, const int* __restrict__ idx,
    unsigned short* __restrict__ abig) {
  int r = blockIdx.x;            // 0..N_-1
  int b = r / K_;
  int tok = idx[r];
  const float* src = base + ((size_t)b * L_ + tok) * D_;
  float4 v = ((const float4*)src)[threadIdx.x];     // 128 thr * 4 = 512
  float ss = v.x * v.x + v.y * v.y + v.z * v.z + v.w * v.w;
  #pragma unroll
  for (int o = 32; o > 0; o >>= 1) ss += __shfl_down(ss, o, 64);
  __shared__ float wsum[2];
  if ((threadIdx.x & 63) == 0) wsum[threadIdx.x >> 6] = ss;
  __syncthreads();
  float total = wsum[0] + wsum[1];
  float inv = 1.0f / (sqrtf(total) + 1e-8f);
  ushort4v o4 = { f2bf(v.x * inv), f2bf(v.y * inv), f2bf(v.z * inv), f2bf(v.w * inv) };
  ((ushort4v*)(abig + (size_t)r * KBIG))[threadIdx.x] = o4;
}

// ---------------- bf16 MFMA GEMM: C[m,n] = A[m,:K] . W[n,:K] + bias[n]
// A bf16 row-major lda, W bf16 row-major [N][K] ldw, C fp32 row-major ldc.
// 128x128 tile, BK=32, 256 threads = 4 waves, wave computes 64x64 via 4x4
// mfma_f32_16x16x32_bf16 tiles. global_load_lds width-16 staging.
// Staging: tile is 128 rows x 32 cols bf16 = 8KB; 256 thr x 16B = 4KB per issue
// -> TWO issues per thread per matrix. Issue q covers row 16*wave+(lane>>2)+64q.
// LDS byte offset = 1024*wave + 16*lane + 4096*q (wave-uniform base + lane*16).
__global__ __launch_bounds__(256) void gemm_mfma_kernel(
    const unsigned short* __restrict__ A, int lda,
    const unsigned short* __restrict__ W, int ldw,
    const float* __restrict__ bias,
    float* __restrict__ C, int ldc, int K) {
  __shared__ unsigned short As[128 * 32];
  __shared__ unsigned short Bs[128 * 32];
  const int tid  = threadIdx.x;
  const int wave = tid >> 6;
  const int lane = tid & 63;
  const int m0 = blockIdx.x * 128;
  const int n0 = blockIdx.y * 128;

  const int srow0 = 16 * wave + (lane >> 2);   // rows 0..63   (issue 0)
  const int srow1 = srow0 + 64;                // rows 64..127 (issue 1)
  const int scol  = (lane & 3) * 8;
  const unsigned short* ag0 = A + (size_t)(m0 + srow0) * lda + scol;
  const unsigned short* ag1 = A + (size_t)(m0 + srow1) * lda + scol;
  const unsigned short* wg0 = W + (size_t)(n0 + srow0) * ldw + scol;
  const unsigned short* wg1 = W + (size_t)(n0 + srow1) * ldw + scol;
  unsigned short* as_dst0 = &As[srow0 * 32 + scol];
  unsigned short* as_dst1 = &As[srow1 * 32 + scol];
  unsigned short* bs_dst0 = &Bs[srow0 * 32 + scol];
  unsigned short* bs_dst1 = &Bs[srow1 * 32 + scol];

  // fragment addresses: A[m=lane&15][k=quad*8+j]
  const int quad = lane >> 4;
  const int l15  = lane & 15;
  const int wm = (wave & 1) * 64;
  const int wn = (wave >> 1) * 64;

  f32x4 acc[4][4];
  #pragma unroll
  for (int i = 0; i < 4; ++i)
    #pragma unroll
    for (int j = 0; j < 4; ++j)
      acc[i][j] = (f32x4)(0.0f);

  for (int k0 = 0; k0 < K; k0 += 32) {
    GLOAD_LDS16(ag0 + k0, as_dst0);
    GLOAD_LDS16(ag1 + k0, as_dst1);
    GLOAD_LDS16(wg0 + k0, bs_dst0);
    GLOAD_LDS16(wg1 + k0, bs_dst1);
    __syncthreads();   // vmcnt(0) drain before barrier covers the LDS writes
    bf16x8 af[4], bfr[4];
    #pragma unroll
    for (int i = 0; i < 4; ++i)
      af[i] = *(const bf16x8*)&As[(wm + 16 * i + l15) * 32 + quad * 8];
    #pragma unroll
    for (int j = 0; j < 4; ++j)
      bfr[j] = *(const bf16x8*)&Bs[(wn + 16 * j + l15) * 32 + quad * 8];
    #pragma unroll
    for (int i = 0; i < 4; ++i)
      #pragma unroll
      for (int j = 0; j < 4; ++j)
        acc[i][j] = __builtin_amdgcn_mfma_f32_16x16x32_bf16(af[i], bfr[j], acc[i][j], 0, 0, 0);
    __syncthreads();
  }

  // epilogue: C/D layout col=lane&15, row=quad*4+reg
  #pragma unroll
  for (int i = 0; i < 4; ++i) {
    int row_base = m0 + wm + 16 * i + quad * 4;
    #pragma unroll
    for (int j = 0; j < 4; ++j) {
      int col = n0 + wn + 16 * j + l15;
      float bb = bias[col];
      #pragma unroll
      for (int r = 0; r < 4; ++r)
        C[(size_t)(row_base + r) * ldc + col] = acc[i][j][r] + bb;
    }
  }
}

// ---------------- BN stats stage A (partial sums per 144-row chunk), h ld=512
__global__ __launch_bounds__(256) void bn_stats1_kernel(
    const float* __restrict__ h, float* __restrict__ partial) {
  int blk = blockIdx.x;          // 128 blocks
  int t = threadIdx.x;
  int r0 = blk * 144;
  float s0 = 0.f, q0 = 0.f, s1 = 0.f, q1 = 0.f;
  for (int i = 0; i < 144; ++i) {
    const float* row = h + (size_t)(r0 + i) * H_;
    float a = row[t], b2 = row[t + 256];
    s0 += a; q0 += a * a; s1 += b2; q1 += b2 * b2;
  }
  partial[blk * 512 + t] = s0;
  partial[blk * 512 + t + 256] = s1;
  partial[65536 + blk * 512 + t] = q0;
  partial[65536 + blk * 512 + t + 256] = q1;
}

// ---------------- BN stats stage B -> mu, rsig
__global__ __launch_bounds__(256) void bn_stats2_kernel(
    const float* __restrict__ partial, float* __restrict__ musig) {
  int c = blockIdx.x * 256 + threadIdx.x;    // 512 threads
  float S = 0.f, Q = 0.f;
  for (int i = 0; i < 128; ++i) {
    S += partial[i * 512 + c];
    Q += partial[65536 + i * 512 + c];
  }
  const float invN = 1.0f / (float)N_;
  float mu = S * invN;
  float var = Q * invN - mu * mu;
  musig[c] = mu;
  musig[512 + c] = rsqrtf(var + 1e-5f);
}

// ---------------- BN apply + ReLU: h fp32 -> Abig[:,512:1024] bf16
__global__ __launch_bounds__(256) void bn_apply_kernel(
    const float* __restrict__ h, unsigned short* __restrict__ abig,
    const float* __restrict__ musig,
    const float* __restrict__ gamma, const float* __restrict__ beta) {
  int gid = blockIdx.x * 256 + threadIdx.x;   // N_*128
  int r = gid >> 7;
  int c4 = gid & 127;
  int c = c4 * 4;
  float4 v = *((const float4*)(h + (size_t)r * H_) + c4);
  float vv[4] = {v.x, v.y, v.z, v.w};
  unsigned short o[4];
  #pragma unroll
  for (int j = 0; j < 4; ++j) {
    float x = (vv[j] - musig[c + j]) * musig[512 + c + j] * gamma[c + j] + beta[c + j];
    o[j] = f2bf(fmaxf(x, 0.0f));
  }
  ushort4v ov = { o[0], o[1], o[2], o[3] };
  *((ushort4v*)(abig + (size_t)r * KBIG + H_) + c4) = ov;
}

// ---------------- max over k rows per batch -> out [B,E]
__global__ __launch_bounds__(256) void maxk_kernel(
    const float* __restrict__ local, float* __restrict__ out) {
  int gid = blockIdx.x * 256 + threadIdx.x;   // 65536
  int b = gid >> 10, e = gid & 1023;
  const float* p = local + (size_t)b * K_ * KBIG + e;
  float m = -INFINITY;
  for (int j = 0; j < K_; ++j) m = fmaxf(m, p[(size_t)j * KBIG]);
  out[gid] = m;
}

extern "C" void kernel_launch(void* const* d_in, const int* in_sizes, int n_in,
                              void* d_out, int out_size, void* d_ws, size_t ws_size,
                              hipStream_t stream) {
  const float* base  = (const float*)d_in[0];   // [64,577,512]
  const float* atten = (const float*)d_in[1];   // [64,577,577]
  const float* fc_w  = (const float*)d_in[2];   // [1024,512]
  const float* fc_b  = (const float*)d_in[3];   // [1024]
  const float* w0    = (const float*)d_in[4];   // [512,512]
  const float* b0    = (const float*)d_in[5];   // [512]
  const float* gamma = (const float*)d_in[6];   // [512]
  const float* beta  = (const float*)d_in[7];   // [512]
  const float* w1    = (const float*)d_in[8];   // [1024,512]
  const float* b1    = (const float*)d_in[9];   // [1024]
  float* out = (float*)d_out;

  char* ws = (char*)d_ws;
  unsigned short* wbig    = (unsigned short*)(ws + OFF_WBIG);
  unsigned short* w0b     = (unsigned short*)(ws + OFF_W0B);
  float*          biasbig = (float*)(ws + OFF_BIASBIG);
  float*          musig   = (float*)(ws + OFF_MUSIG);
  int*            idx     = (int*)  (ws + OFF_IDX);
  float*          partial = (float*)(ws + OFF_PART);
  unsigned short* abig    = (unsigned short*)(ws + OFF_ABIG);
  float*          h       = (float*)(ws + OFF_H);
  float*          local   = (float*)(ws + OFF_LOCAL);

  // 1. pack fused weight/bias (bf16)
  prep_kernel<<<1280, 256, 0, stream>>>(fc_w, fc_b, w0, w1, b1, wbig, w0b, biasbig);
  // 2. top-k selection
  topk_kernel<<<B_, 256, 0, stream>>>(atten, idx);
  // 3. gather + l2norm -> Abig[:,0:512] bf16
  gather_norm_kernel<<<N_, 128, 0, stream>>>(base, idx, abig);
  // 4. GEMM1: h = feats @ w0^T + b0 (fp32 out)
  {
    dim3 grid(N_ / 128, H_ / 128);
    gemm_mfma_kernel<<<grid, 256, 0, stream>>>(abig, KBIG, w0b, D_, b0, h, H_, D_);
  }
  // 5-6. BN stats
  bn_stats1_kernel<<<128, 256, 0, stream>>>(h, partial);
  bn_stats2_kernel<<<2, 256, 0, stream>>>(partial, musig);
  // 7. BN apply + ReLU -> Abig[:,512:1024] bf16
  bn_apply_kernel<<<(N_ * 128) / 256, 256, 0, stream>>>(h, abig, musig, gamma, beta);
  // 8. fused GEMM2: local = [feats|hbn] @ [fc_w|w1]^T + (fc_b+b1)
  {
    dim3 grid(N_ / 128, E_ / 128);
    gemm_mfma_kernel<<<grid, 256, 0, stream>>>(abig, KBIG, wbig, KBIG, biasbig,
                                               local, KBIG, KBIG);
  }
  // 9. max over k per batch
  maxk_kernel<<<(B_ * E_) / 256, 256, 0, stream>>>(local, out);
}

// Round 4
// 318.159 us; speedup vs baseline: 3.2569x; 1.1187x over previous
//
#include <hip/hip_runtime.h>
#include <math.h>

// Problem constants
#define B_   64
#define L_   577
#define D_   512
#define E_   1024
#define H_   512
#define K_   288            // selected tokens per batch
#define N_   (B_ * K_)      // 18432 total rows
#define KBIG 1024           // concatenated K for fused GEMM2
#define MTILES (N_ / 128)   // 144

typedef __attribute__((ext_vector_type(8))) __bf16 bf16x8;
typedef __attribute__((ext_vector_type(4))) float f32x4;
typedef __attribute__((ext_vector_type(4))) unsigned short ushort4v;

// ---------------- workspace layout (bytes) ----------------
#define OFF_WBIG    0                    // 1024*1024 bf16 = 2,097,152
#define OFF_W0B     2097152              // 512*512 bf16   =   524,288
#define OFF_BIASBIG 2621440              // 1024 f32
#define OFF_MUSIG   2625536              // 1024 f32 (mu, rsig)
#define OFF_IDX     2629632              // 18432 i32 = 73,728
#define OFF_PSUM    2703360              // 144*512 f32 = 294,912
#define OFF_PSQ     2998272              // 144*512 f32 = 294,912
#define OFF_OUTENC  3293184              // 64*1024 u32 = 262,144
#define OFF_ABIG    3555328              // N*1024 bf16 = 37,748,736
#define OFF_H       (3555328 + (size_t)N_ * KBIG * 2)   // N*512 f32

static __device__ __forceinline__ unsigned short f2bf(float f) {
  unsigned int u = __builtin_bit_cast(unsigned int, f);
  u = (u + 0x7fffu + ((u >> 16) & 1u)) >> 16;
  return (unsigned short)u;
}

// monotone fp32 <-> uint encoding for atomicMax on floats
static __device__ __forceinline__ unsigned int encf(float f) {
  unsigned int u = __builtin_bit_cast(unsigned int, f);
  return (u & 0x80000000u) ? ~u : (u | 0x80000000u);
}
static __device__ __forceinline__ float decf(unsigned int e) {
  unsigned int u = (e & 0x80000000u) ? (e ^ 0x80000000u) : ~e;
  return __builtin_bit_cast(float, u);
}

#define GLOAD_LDS16(g, l)                                          \
  __builtin_amdgcn_global_load_lds(                                \
      (const __attribute__((address_space(1))) void*)(g),          \
      (__attribute__((address_space(3))) void*)(l), 16, 0, 0)

// ---------------- kernel 1: pack Wbig(bf16)=[fc_w|mlp_w1], biasbig=fc_b+b1,
//                  W0(bf16), and zero outenc
__global__ __launch_bounds__(256) void prep_kernel(
    const float* __restrict__ fc_w, const float* __restrict__ fc_b,
    const float* __restrict__ w0,   const float* __restrict__ w1,
    const float* __restrict__ b1,
    unsigned short* __restrict__ wbig, unsigned short* __restrict__ w0b,
    float* __restrict__ biasbig, unsigned int* __restrict__ outenc) {
  int gid = blockIdx.x * 256 + threadIdx.x;      // 327680 total
  if (gid < 65536) outenc[gid] = 0u;             // < encode of any real value
  if (gid < 262144) {                            // wbig: 1024 rows x 256 f4-cols
    int e  = gid >> 8;
    int c4 = gid & 255;
    float4 v;
    if (c4 < 128) v = ((const float4*)(fc_w + e * D_))[c4];
    else          v = ((const float4*)(w1   + e * H_))[c4 - 128];
    ushort4v o = { f2bf(v.x), f2bf(v.y), f2bf(v.z), f2bf(v.w) };
    ((ushort4v*)wbig)[gid] = o;
    if (gid < E_) biasbig[gid] = fc_b[gid] + b1[gid];
  } else {                                       // w0b: 512x512
    int idx = gid - 262144;                      // 65536
    float4 v = ((const float4*)w0)[idx];
    ushort4v o = { f2bf(v.x), f2bf(v.y), f2bf(v.z), f2bf(v.w) };
    ((ushort4v*)w0b)[idx] = o;
  }
}

// ---------------- kernel 2: stable top-k per batch via rank
__global__ __launch_bounds__(256) void topk_kernel(
    const float* __restrict__ atten, int* __restrict__ idx) {
  __shared__ float s[L_];
  int b = blockIdx.x;
  const float* row = atten + (size_t)b * L_ * L_;   // atten[b][0][:]
  for (int i = threadIdx.x; i < L_; i += 256) s[i] = (i == 0) ? -1.0f : row[i];
  __syncthreads();
  for (int i = threadIdx.x; i < L_; i += 256) {
    float si = s[i];
    int rank = 0;
    for (int j = 0; j < L_; ++j) {
      float sj = s[j];
      rank += (sj > si) || (sj == si && j < i);
    }
    if (rank < K_) idx[b * K_ + rank] = i;
  }
}

// ---------------- kernel 3: gather + L2 normalize -> Abig[:,0:512] (bf16)
__global__ __launch_bounds__(128) void gather_norm_kernel(
    const float* __restrict__ base, const int* __restrict__ idx,
    unsigned short* __restrict__ abig) {
  int r = blockIdx.x;            // 0..N_-1
  int b = r / K_;
  int tok = idx[r];
  const float* src = base + ((size_t)b * L_ + tok) * D_;
  float4 v = ((const float4*)src)[threadIdx.x];     // 128 thr * 4 = 512
  float ss = v.x * v.x + v.y * v.y + v.z * v.z + v.w * v.w;
  #pragma unroll
  for (int o = 32; o > 0; o >>= 1) ss += __shfl_down(ss, o, 64);
  __shared__ float wsum[2];
  if ((threadIdx.x & 63) == 0) wsum[threadIdx.x >> 6] = ss;
  __syncthreads();
  float total = wsum[0] + wsum[1];
  float inv = 1.0f / (sqrtf(total) + 1e-8f);
  ushort4v o4 = { f2bf(v.x * inv), f2bf(v.y * inv), f2bf(v.z * inv), f2bf(v.w * inv) };
  ((ushort4v*)(abig + (size_t)r * KBIG))[threadIdx.x] = o4;
}

// ---------------- bf16 MFMA GEMM, 128x128 tile, BK=32, 4 waves.
// XOR-swizzled LDS: slot c of row holds global col-block (c ^ ((row>>1)&3)).
// Staging global col = ((lane&3) ^ ((lane>>3)&3))*8; LDS dst stays
// wave-uniform base + 16*lane (m104 contiguity rule satisfied).
// MODE 0 (GEMM1): write C (fp32) + per-mtile BN partial sum/sumsq.
// MODE 1 (GEMM2): no C write; fused per-batch column max via atomicMax(enc).
template <int MODE>
__global__ __launch_bounds__(256) void gemm_mfma_kernel(
    const unsigned short* __restrict__ A, int lda,
    const unsigned short* __restrict__ W, int ldw,
    const float* __restrict__ bias,
    float* __restrict__ C, int ldc, int K,
    float* __restrict__ psum, float* __restrict__ psq,
    unsigned int* __restrict__ outenc) {
  __shared__ unsigned short As[128 * 32];
  __shared__ unsigned short Bs[128 * 32];
  __shared__ float s_sum[4][64];
  __shared__ float s_sq[4][64];
  const int tid  = threadIdx.x;
  const int wave = tid >> 6;
  const int lane = tid & 63;
  const int m0 = blockIdx.x * 128;
  const int n0 = blockIdx.y * 128;

  const int srow0 = 16 * wave + (lane >> 2);   // rows 0..63   (issue 0)
  const int srow1 = srow0 + 64;                // rows 64..127 (issue 1)
  const int gcol  = (((lane & 3) ^ ((lane >> 3) & 3))) * 8;  // swizzled source col
  const int lcol  = (lane & 3) * 8;                          // dense LDS slot
  const unsigned short* ag0 = A + (size_t)(m0 + srow0) * lda + gcol;
  const unsigned short* ag1 = A + (size_t)(m0 + srow1) * lda + gcol;
  const unsigned short* wg0 = W + (size_t)(n0 + srow0) * ldw + gcol;
  const unsigned short* wg1 = W + (size_t)(n0 + srow1) * ldw + gcol;
  unsigned short* as_dst0 = &As[srow0 * 32 + lcol];
  unsigned short* as_dst1 = &As[srow1 * 32 + lcol];
  unsigned short* bs_dst0 = &Bs[srow0 * 32 + lcol];
  unsigned short* bs_dst1 = &Bs[srow1 * 32 + lcol];

  const int quad = lane >> 4;
  const int l15  = lane & 15;
  const int wm = (wave & 1) * 64;
  const int wn = (wave >> 1) * 64;
  const int rswz = (l15 >> 1) & 3;             // read-side swizzle (== (row>>1)&3)

  f32x4 acc[4][4];
  #pragma unroll
  for (int i = 0; i < 4; ++i)
    #pragma unroll
    for (int j = 0; j < 4; ++j)
      acc[i][j] = (f32x4)(0.0f);

  for (int k0 = 0; k0 < K; k0 += 32) {
    GLOAD_LDS16(ag0 + k0, as_dst0);
    GLOAD_LDS16(ag1 + k0, as_dst1);
    GLOAD_LDS16(wg0 + k0, bs_dst0);
    GLOAD_LDS16(wg1 + k0, bs_dst1);
    __syncthreads();
    bf16x8 af[4], bfr[4];
    #pragma unroll
    for (int i = 0; i < 4; ++i)
      af[i] = *(const bf16x8*)&As[(wm + 16 * i + l15) * 32 + (quad ^ rswz) * 8];
    #pragma unroll
    for (int j = 0; j < 4; ++j)
      bfr[j] = *(const bf16x8*)&Bs[(wn + 16 * j + l15) * 32 + (quad ^ rswz) * 8];
    #pragma unroll
    for (int i = 0; i < 4; ++i)
      #pragma unroll
      for (int j = 0; j < 4; ++j)
        acc[i][j] = __builtin_amdgcn_mfma_f32_16x16x32_bf16(af[i], bfr[j], acc[i][j], 0, 0, 0);
    __syncthreads();
  }

  // epilogue: C/D layout col=lane&15, row=quad*4+reg
  if (MODE == 0) {
    // write C + per-column partial sum/sumsq over this block's 128 rows
    #pragma unroll
    for (int j = 0; j < 4; ++j) {
      int col = n0 + wn + 16 * j + l15;
      float bb = bias[col];
      float sm = 0.f, sq = 0.f;
      #pragma unroll
      for (int i = 0; i < 4; ++i) {
        int row_base = m0 + wm + 16 * i + quad * 4;
        #pragma unroll
        for (int r = 0; r < 4; ++r) {
          float v = acc[i][j][r] + bb;
          C[(size_t)(row_base + r) * ldc + col] = v;
          sm += v; sq += v * v;
        }
      }
      sm += __shfl_xor(sm, 16, 64); sm += __shfl_xor(sm, 32, 64);
      sq += __shfl_xor(sq, 16, 64); sq += __shfl_xor(sq, 32, 64);
      if (quad == 0) { s_sum[wave][j * 16 + l15] = sm; s_sq[wave][j * 16 + l15] = sq; }
    }
    __syncthreads();
    if (tid < 128) {
      int half = tid >> 6;          // 0: waves 0,1 (cols 0..63); 1: waves 2,3
      int c = tid & 63;
      float sm = s_sum[half * 2][c] + s_sum[half * 2 + 1][c];
      float sq = s_sq[half * 2][c] + s_sq[half * 2 + 1][c];
      int col = n0 + half * 64 + c;
      psum[blockIdx.x * H_ + col] = sm;
      psq [blockIdx.x * H_ + col] = sq;
    }
  } else {
    // fused max over rows, grouped by batch (16-row bands are batch-uniform)
    #pragma unroll
    for (int j = 0; j < 4; ++j) {
      int col = n0 + wn + 16 * j + l15;
      float bb = bias[col];
      float m[4];
      #pragma unroll
      for (int i = 0; i < 4; ++i) {
        float v = fmaxf(fmaxf(acc[i][j][0], acc[i][j][1]),
                        fmaxf(acc[i][j][2], acc[i][j][3]));
        m[i] = v + bb;
      }
      #pragma unroll
      for (int i = 0; i < 4; ++i) {
        m[i] = fmaxf(m[i], __shfl_xor(m[i], 16, 64));
        m[i] = fmaxf(m[i], __shfl_xor(m[i], 32, 64));
      }
      if (quad == 0) {
        int base = m0 + wm;
        int b0i = (base) / K_;
        float cur = m[0]; int cb = b0i;
        #pragma unroll
        for (int i = 1; i < 4; ++i) {
          int bi = (base + 16 * i) / K_;
          if (bi == cb) cur = fmaxf(cur, m[i]);
          else { atomicMax(&outenc[cb * E_ + col], encf(cur)); cur = m[i]; cb = bi; }
        }
        atomicMax(&outenc[cb * E_ + col], encf(cur));
      }
    }
  }
}

// ---------------- BN stats stage B: reduce per-mtile partials -> mu, rsig
__global__ __launch_bounds__(256) void bn_stats2_kernel(
    const float* __restrict__ psum, const float* __restrict__ psq,
    float* __restrict__ musig) {
  int c = blockIdx.x * 256 + threadIdx.x;    // 512 threads
  float S = 0.f, Q = 0.f;
  for (int mx = 0; mx < MTILES; ++mx) {
    S += psum[mx * H_ + c];
    Q += psq [mx * H_ + c];
  }
  const float invN = 1.0f / (float)N_;
  float mu = S * invN;
  float var = Q * invN - mu * mu;
  musig[c] = mu;
  musig[512 + c] = rsqrtf(var + 1e-5f);
}

// ---------------- BN apply + ReLU: h fp32 -> Abig[:,512:1024] bf16
__global__ __launch_bounds__(256) void bn_apply_kernel(
    const float* __restrict__ h, unsigned short* __restrict__ abig,
    const float* __restrict__ musig,
    const float* __restrict__ gamma, const float* __restrict__ beta) {
  int gid = blockIdx.x * 256 + threadIdx.x;   // N_*128
  int r = gid >> 7;
  int c4 = gid & 127;
  int c = c4 * 4;
  float4 v = *((const float4*)(h + (size_t)r * H_) + c4);
  float vv[4] = {v.x, v.y, v.z, v.w};
  unsigned short o[4];
  #pragma unroll
  for (int j = 0; j < 4; ++j) {
    float x = (vv[j] - musig[c + j]) * musig[512 + c + j] * gamma[c + j] + beta[c + j];
    o[j] = f2bf(fmaxf(x, 0.0f));
  }
  ushort4v ov = { o[0], o[1], o[2], o[3] };
  *((ushort4v*)(abig + (size_t)r * KBIG + H_) + c4) = ov;
}

// ---------------- decode encoded maxes -> d_out
__global__ __launch_bounds__(256) void decode_kernel(
    const unsigned int* __restrict__ outenc, float* __restrict__ out) {
  int gid = blockIdx.x * 256 + threadIdx.x;   // 65536
  out[gid] = decf(outenc[gid]);
}

extern "C" void kernel_launch(void* const* d_in, const int* in_sizes, int n_in,
                              void* d_out, int out_size, void* d_ws, size_t ws_size,
                              hipStream_t stream) {
  const float* base  = (const float*)d_in[0];   // [64,577,512]
  const float* atten = (const float*)d_in[1];   // [64,577,577]
  const float* fc_w  = (const float*)d_in[2];   // [1024,512]
  const float* fc_b  = (const float*)d_in[3];   // [1024]
  const float* w0    = (const float*)d_in[4];   // [512,512]
  const float* b0    = (const float*)d_in[5];   // [512]
  const float* gamma = (const float*)d_in[6];   // [512]
  const float* beta  = (const float*)d_in[7];   // [512]
  const float* w1    = (const float*)d_in[8];   // [1024,512]
  const float* b1    = (const float*)d_in[9];   // [1024]
  float* out = (float*)d_out;

  char* ws = (char*)d_ws;
  unsigned short* wbig    = (unsigned short*)(ws + OFF_WBIG);
  unsigned short* w0b     = (unsigned short*)(ws + OFF_W0B);
  float*          biasbig = (float*)(ws + OFF_BIASBIG);
  float*          musig   = (float*)(ws + OFF_MUSIG);
  int*            idx     = (int*)  (ws + OFF_IDX);
  float*          psum    = (float*)(ws + OFF_PSUM);
  float*          psq     = (float*)(ws + OFF_PSQ);
  unsigned int*   outenc  = (unsigned int*)(ws + OFF_OUTENC);
  unsigned short* abig    = (unsigned short*)(ws + OFF_ABIG);
  float*          h       = (float*)(ws + OFF_H);

  // 1. pack fused weight/bias (bf16) + zero outenc
  prep_kernel<<<1280, 256, 0, stream>>>(fc_w, fc_b, w0, w1, b1, wbig, w0b,
                                        biasbig, outenc);
  // 2. top-k selection
  topk_kernel<<<B_, 256, 0, stream>>>(atten, idx);
  // 3. gather + l2norm -> Abig[:,0:512] bf16
  gather_norm_kernel<<<N_, 128, 0, stream>>>(base, idx, abig);
  // 4. GEMM1: h = feats @ w0^T + b0 (fp32 out) + fused BN partial stats
  {
    dim3 grid(MTILES, H_ / 128);
    gemm_mfma_kernel<0><<<grid, 256, 0, stream>>>(abig, KBIG, w0b, D_, b0,
                                                  h, H_, D_, psum, psq, nullptr);
  }
  // 5. BN stats reduce
  bn_stats2_kernel<<<2, 256, 0, stream>>>(psum, psq, musig);
  // 6. BN apply + ReLU -> Abig[:,512:1024] bf16
  bn_apply_kernel<<<(N_ * 128) / 256, 256, 0, stream>>>(h, abig, musig, gamma, beta);
  // 7. fused GEMM2 + per-batch column max (no local materialization)
  {
    dim3 grid(MTILES, E_ / 128);
    gemm_mfma_kernel<1><<<grid, 256, 0, stream>>>(abig, KBIG, wbig, KBIG, biasbig,
                                                  nullptr, 0, KBIG, nullptr, nullptr,
                                                  outenc);
  }
  // 8. decode -> out
  decode_kernel<<<(B_ * E_) / 256, 256, 0, stream>>>(outenc, out);
}

// Round 5
// 292.794 us; speedup vs baseline: 3.5390x; 1.0866x over previous
//
#include <hip/hip_runtime.h>
#include <math.h>

// Problem constants
#define B_   64
#define L_   577
#define D_   512
#define E_   1024
#define H_   512
#define K_   288            // selected tokens per batch
#define N_   (B_ * K_)      // 18432 total rows
#define KBIG 1024           // concatenated K for fused GEMM2
#define MTILES (N_ / 128)   // 144

typedef __attribute__((ext_vector_type(8))) __bf16 bf16x8;
typedef __attribute__((ext_vector_type(4))) float f32x4;
typedef __attribute__((ext_vector_type(4))) unsigned short ushort4v;
typedef __attribute__((ext_vector_type(8))) unsigned short ushort8v;

// ---------------- workspace layout (bytes) ----------------
#define OFF_WBIG    0                    // 1024*1024 bf16 = 2,097,152
#define OFF_W0B     2097152              // 512*512 bf16   =   524,288
#define OFF_BIASBIG 2621440              // 1024 f32
#define OFF_SCSH    2625536              // 1024 f32 (sc=rsig*gamma, sh=beta-mu*sc)
#define OFF_IDX     2629632              // 18432 i32 = 73,728
#define OFF_PSUM    2703360              // 144*512 f32 = 294,912
#define OFF_PSQ     2998272              // 144*512 f32 = 294,912
#define OFF_OUTENC  3293184              // 64*1024 u32 = 262,144
#define OFF_ABIG    3555328              // N*1024 bf16 = 37,748,736

static __device__ __forceinline__ unsigned short f2bf(float f) {
  unsigned int u = __builtin_bit_cast(unsigned int, f);
  u = (u + 0x7fffu + ((u >> 16) & 1u)) >> 16;
  return (unsigned short)u;
}
static __device__ __forceinline__ float bf2f(unsigned short s) {
  unsigned int u = ((unsigned int)s) << 16;
  return __builtin_bit_cast(float, u);
}

// monotone fp32 <-> uint encoding for atomicMax on floats
static __device__ __forceinline__ unsigned int encf(float f) {
  unsigned int u = __builtin_bit_cast(unsigned int, f);
  return (u & 0x80000000u) ? ~u : (u | 0x80000000u);
}
static __device__ __forceinline__ float decf(unsigned int e) {
  unsigned int u = (e & 0x80000000u) ? (e ^ 0x80000000u) : ~e;
  return __builtin_bit_cast(float, u);
}

#define GLOAD_LDS16(g, l)                                          \
  __builtin_amdgcn_global_load_lds(                                \
      (const __attribute__((address_space(1))) void*)(g),          \
      (__attribute__((address_space(3))) void*)(l), 16, 0, 0)

// ---------------- kernel 1: pack Wbig(bf16)=[fc_w|mlp_w1], biasbig=fc_b+b1,
//                  W0(bf16), and zero outenc
__global__ __launch_bounds__(256) void prep_kernel(
    const float* __restrict__ fc_w, const float* __restrict__ fc_b,
    const float* __restrict__ w0,   const float* __restrict__ w1,
    const float* __restrict__ b1,
    unsigned short* __restrict__ wbig, unsigned short* __restrict__ w0b,
    float* __restrict__ biasbig, unsigned int* __restrict__ outenc) {
  int gid = blockIdx.x * 256 + threadIdx.x;      // 327680 total
  if (gid < 65536) outenc[gid] = 0u;             // < encode of any real value
  if (gid < 262144) {                            // wbig: 1024 rows x 256 f4-cols
    int e  = gid >> 8;
    int c4 = gid & 255;
    float4 v;
    if (c4 < 128) v = ((const float4*)(fc_w + e * D_))[c4];
    else          v = ((const float4*)(w1   + e * H_))[c4 - 128];
    ushort4v o = { f2bf(v.x), f2bf(v.y), f2bf(v.z), f2bf(v.w) };
    ((ushort4v*)wbig)[gid] = o;
    if (gid < E_) biasbig[gid] = fc_b[gid] + b1[gid];
  } else {                                       // w0b: 512x512
    int idx = gid - 262144;                      // 65536
    float4 v = ((const float4*)w0)[idx];
    ushort4v o = { f2bf(v.x), f2bf(v.y), f2bf(v.z), f2bf(v.w) };
    ((ushort4v*)w0b)[idx] = o;
  }
}

// ---------------- kernel 2: stable top-k per batch via rank
__global__ __launch_bounds__(256) void topk_kernel(
    const float* __restrict__ atten, int* __restrict__ idx) {
  __shared__ float s[L_];
  int b = blockIdx.x;
  const float* row = atten + (size_t)b * L_ * L_;   // atten[b][0][:]
  for (int i = threadIdx.x; i < L_; i += 256) s[i] = (i == 0) ? -1.0f : row[i];
  __syncthreads();
  for (int i = threadIdx.x; i < L_; i += 256) {
    float si = s[i];
    int rank = 0;
    for (int j = 0; j < L_; ++j) {
      float sj = s[j];
      rank += (sj > si) || (sj == si && j < i);
    }
    if (rank < K_) idx[b * K_ + rank] = i;
  }
}

// ---------------- kernel 3: gather + L2 normalize -> Abig[:,0:512] (bf16)
__global__ __launch_bounds__(128) void gather_norm_kernel(
    const float* __restrict__ base, const int* __restrict__ idx,
    unsigned short* __restrict__ abig) {
  int r = blockIdx.x;            // 0..N_-1
  int b = r / K_;
  int tok = idx[r];
  const float* src = base + ((size_t)b * L_ + tok) * D_;
  float4 v = ((const float4*)src)[threadIdx.x];     // 128 thr * 4 = 512
  float ss = v.x * v.x + v.y * v.y + v.z * v.z + v.w * v.w;
  #pragma unroll
  for (int o = 32; o > 0; o >>= 1) ss += __shfl_down(ss, o, 64);
  __shared__ float wsum[2];
  if ((threadIdx.x & 63) == 0) wsum[threadIdx.x >> 6] = ss;
  __syncthreads();
  float total = wsum[0] + wsum[1];
  float inv = 1.0f / (sqrtf(total) + 1e-8f);
  ushort4v o4 = { f2bf(v.x * inv), f2bf(v.y * inv), f2bf(v.z * inv), f2bf(v.w * inv) };
  ((ushort4v*)(abig + (size_t)r * KBIG))[threadIdx.x] = o4;
}

// ---------------- bf16 MFMA GEMM, 128x128 tile, BK=64, 4 waves.
// LDS tile: 128 rows x 64 cols bf16, 8 slots of 8 cols per row (128B rows).
// XOR swizzle: slot s of row r holds global col-block s ^ (r&7).
// Staging (4 issues q per matrix): linear idx = q*256 + wave*64 + lane;
// row = q*32 + wave*8 + (lane>>3); LDS dst = base + 16*lane (m104 rule);
// lane fetches global col-block (lane&7) ^ ((lane>>3)&7) [== slot ^ (row&7)].
// Reader: frag for global k-block (4kk+quad) at slot (4kk+quad)^(l15&7);
// each lane-octet covers 8 distinct bank groups -> conflict-free.
// MODE 0 (GEMM1): write pre-BN h as bf16 + per-mtile BN partial sum/sumsq.
// MODE 1 (GEMM2): no C write; fused per-batch column max via atomicMax(enc).
template <int MODE>
__global__ __launch_bounds__(256) void gemm_mfma_kernel(
    const unsigned short* __restrict__ A, int lda,
    const unsigned short* __restrict__ W, int ldw,
    const float* __restrict__ bias,
    unsigned short* __restrict__ Cbf, int ldc, int K,
    float* __restrict__ psum, float* __restrict__ psq,
    unsigned int* __restrict__ outenc) {
  __shared__ unsigned short As[128 * 64];
  __shared__ unsigned short Bs[128 * 64];
  __shared__ float s_sum[4][64];
  __shared__ float s_sq[4][64];
  const int tid  = threadIdx.x;
  const int wave = tid >> 6;
  const int lane = tid & 63;
  const int m0 = blockIdx.x * 128;
  const int n0 = blockIdx.y * 128;

  const int srow = wave * 8 + (lane >> 3);                 // + q*32
  const int g8   = ((lane & 7) ^ ((lane >> 3) & 7)) * 8;   // swizzled global col
  const int ldst = (wave * 64 + lane) * 8;                 // + q*2048 (ushorts)

  const int quad = lane >> 4;
  const int l15  = lane & 15;
  const int wm = (wave & 1) * 64;
  const int wn = (wave >> 1) * 64;
  const int slot0 = quad ^ (l15 & 7);          // kk adds XOR 4

  f32x4 acc[4][4];
  #pragma unroll
  for (int i = 0; i < 4; ++i)
    #pragma unroll
    for (int j = 0; j < 4; ++j)
      acc[i][j] = (f32x4)(0.0f);

  for (int k0 = 0; k0 < K; k0 += 64) {
    #pragma unroll
    for (int q = 0; q < 4; ++q) {
      GLOAD_LDS16(A + (size_t)(m0 + q * 32 + srow) * lda + k0 + g8,
                  &As[q * 2048 + ldst]);
      GLOAD_LDS16(W + (size_t)(n0 + q * 32 + srow) * ldw + k0 + g8,
                  &Bs[q * 2048 + ldst]);
    }
    __syncthreads();
    #pragma unroll
    for (int kk = 0; kk < 2; ++kk) {
      const int slot = slot0 ^ (kk * 4);
      bf16x8 af[4], bfr[4];
      #pragma unroll
      for (int i = 0; i < 4; ++i)
        af[i] = *(const bf16x8*)&As[(wm + 16 * i + l15) * 64 + slot * 8];
      #pragma unroll
      for (int j = 0; j < 4; ++j)
        bfr[j] = *(const bf16x8*)&Bs[(wn + 16 * j + l15) * 64 + slot * 8];
      #pragma unroll
      for (int i = 0; i < 4; ++i)
        #pragma unroll
        for (int j = 0; j < 4; ++j)
          acc[i][j] = __builtin_amdgcn_mfma_f32_16x16x32_bf16(af[i], bfr[j], acc[i][j], 0, 0, 0);
    }
    __syncthreads();
  }

  // epilogue: C/D layout col=lane&15, row=quad*4+reg
  if (MODE == 0) {
    // write pre-BN h (bf16) + per-column partial sum/sumsq over 128 rows
    #pragma unroll
    for (int j = 0; j < 4; ++j) {
      int col = n0 + wn + 16 * j + l15;
      float bb = bias[col];
      float sm = 0.f, sq = 0.f;
      #pragma unroll
      for (int i = 0; i < 4; ++i) {
        int row_base = m0 + wm + 16 * i + quad * 4;
        #pragma unroll
        for (int r = 0; r < 4; ++r) {
          float v = acc[i][j][r] + bb;
          Cbf[(size_t)(row_base + r) * ldc + col] = f2bf(v);
          sm += v; sq += v * v;
        }
      }
      sm += __shfl_xor(sm, 16, 64); sm += __shfl_xor(sm, 32, 64);
      sq += __shfl_xor(sq, 16, 64); sq += __shfl_xor(sq, 32, 64);
      if (quad == 0) { s_sum[wave][j * 16 + l15] = sm; s_sq[wave][j * 16 + l15] = sq; }
    }
    __syncthreads();
    if (tid < 128) {
      int half = tid >> 6;          // 0: waves 0,1 (cols 0..63); 1: waves 2,3
      int c = tid & 63;
      float sm = s_sum[half * 2][c] + s_sum[half * 2 + 1][c];
      float sq = s_sq[half * 2][c] + s_sq[half * 2 + 1][c];
      int col = n0 + half * 64 + c;
      psum[blockIdx.x * H_ + col] = sm;
      psq [blockIdx.x * H_ + col] = sq;
    }
  } else {
    // fused max over rows, grouped by batch (16-row bands are batch-uniform)
    #pragma unroll
    for (int j = 0; j < 4; ++j) {
      int col = n0 + wn + 16 * j + l15;
      float bb = bias[col];
      float m[4];
      #pragma unroll
      for (int i = 0; i < 4; ++i) {
        float v = fmaxf(fmaxf(acc[i][j][0], acc[i][j][1]),
                        fmaxf(acc[i][j][2], acc[i][j][3]));
        m[i] = v + bb;
      }
      #pragma unroll
      for (int i = 0; i < 4; ++i) {
        m[i] = fmaxf(m[i], __shfl_xor(m[i], 16, 64));
        m[i] = fmaxf(m[i], __shfl_xor(m[i], 32, 64));
      }
      if (quad == 0) {
        int base = m0 + wm;
        int b0i = (base) / K_;
        float cur = m[0]; int cb = b0i;
        #pragma unroll
        for (int i = 1; i < 4; ++i) {
          int bi = (base + 16 * i) / K_;
          if (bi == cb) cur = fmaxf(cur, m[i]);
          else { atomicMax(&outenc[cb * E_ + col], encf(cur)); cur = m[i]; cb = bi; }
        }
        atomicMax(&outenc[cb * E_ + col], encf(cur));
      }
    }
  }
}

// ---------------- BN stats reduce -> sc = rsig*gamma, sh = beta - mu*sc
__global__ __launch_bounds__(256) void bn_stats2_kernel(
    const float* __restrict__ psum, const float* __restrict__ psq,
    const float* __restrict__ gamma, const float* __restrict__ beta,
    float* __restrict__ scsh) {
  __shared__ float ls[8][32], lq[8][32];
  int c32 = threadIdx.x & 31;
  int slice = threadIdx.x >> 5;               // 8 slices x 18 mtiles = 144
  int c = blockIdx.x * 32 + c32;              // 16 blocks
  float S = 0.f, Q = 0.f;
  for (int i = 0; i < 18; ++i) {
    int mx = slice * 18 + i;
    S += psum[mx * H_ + c];
    Q += psq [mx * H_ + c];
  }
  ls[slice][c32] = S; lq[slice][c32] = Q;
  __syncthreads();
  if (slice == 0) {
    float St = 0.f, Qt = 0.f;
    #pragma unroll
    for (int s = 0; s < 8; ++s) { St += ls[s][c32]; Qt += lq[s][c32]; }
    const float invN = 1.0f / (float)N_;
    float mu = St * invN;
    float var = Qt * invN - mu * mu;
    float sc = rsqrtf(var + 1e-5f) * gamma[c];
    scsh[c] = sc;
    scsh[512 + c] = beta[c] - mu * sc;
  }
}

// ---------------- BN apply + ReLU, bf16 in-place on Abig[:,512:1024]
__global__ __launch_bounds__(256) void bn_apply_kernel(
    unsigned short* __restrict__ abig, const float* __restrict__ scsh) {
  int gid = blockIdx.x * 256 + threadIdx.x;   // N_*64 threads, 8 elems each
  int r = gid >> 6;
  int c8 = gid & 63;
  int c = c8 * 8;
  ushort8v* p = (ushort8v*)(abig + (size_t)r * KBIG + H_) + c8;
  ushort8v v = *p;
  float4 sca = *(const float4*)&scsh[c];
  float4 scb = *(const float4*)&scsh[c + 4];
  float4 sha = *(const float4*)&scsh[512 + c];
  float4 shb = *(const float4*)&scsh[512 + c + 4];
  float sc[8] = {sca.x, sca.y, sca.z, sca.w, scb.x, scb.y, scb.z, scb.w};
  float sh[8] = {sha.x, sha.y, sha.z, sha.w, shb.x, shb.y, shb.z, shb.w};
  ushort8v o;
  #pragma unroll
  for (int j = 0; j < 8; ++j) {
    float x = bf2f(v[j]);
    o[j] = f2bf(fmaxf(x * sc[j] + sh[j], 0.0f));
  }
  *p = o;
}

// ---------------- decode encoded maxes -> d_out
__global__ __launch_bounds__(256) void decode_kernel(
    const unsigned int* __restrict__ outenc, float* __restrict__ out) {
  int gid = blockIdx.x * 256 + threadIdx.x;   // 65536
  out[gid] = decf(outenc[gid]);
}

extern "C" void kernel_launch(void* const* d_in, const int* in_sizes, int n_in,
                              void* d_out, int out_size, void* d_ws, size_t ws_size,
                              hipStream_t stream) {
  const float* base  = (const float*)d_in[0];   // [64,577,512]
  const float* atten = (const float*)d_in[1];   // [64,577,577]
  const float* fc_w  = (const float*)d_in[2];   // [1024,512]
  const float* fc_b  = (const float*)d_in[3];   // [1024]
  const float* w0    = (const float*)d_in[4];   // [512,512]
  const float* b0    = (const float*)d_in[5];   // [512]
  const float* gamma = (const float*)d_in[6];   // [512]
  const float* beta  = (const float*)d_in[7];   // [512]
  const float* w1    = (const float*)d_in[8];   // [1024,512]
  const float* b1    = (const float*)d_in[9];   // [1024]
  float* out = (float*)d_out;

  char* ws = (char*)d_ws;
  unsigned short* wbig    = (unsigned short*)(ws + OFF_WBIG);
  unsigned short* w0b     = (unsigned short*)(ws + OFF_W0B);
  float*          biasbig = (float*)(ws + OFF_BIASBIG);
  float*          scsh    = (float*)(ws + OFF_SCSH);
  int*            idx     = (int*)  (ws + OFF_IDX);
  float*          psum    = (float*)(ws + OFF_PSUM);
  float*          psq     = (float*)(ws + OFF_PSQ);
  unsigned int*   outenc  = (unsigned int*)(ws + OFF_OUTENC);
  unsigned short* abig    = (unsigned short*)(ws + OFF_ABIG);

  // 1. pack fused weight/bias (bf16) + zero outenc
  prep_kernel<<<1280, 256, 0, stream>>>(fc_w, fc_b, w0, w1, b1, wbig, w0b,
                                        biasbig, outenc);
  // 2. top-k selection
  topk_kernel<<<B_, 256, 0, stream>>>(atten, idx);
  // 3. gather + l2norm -> Abig[:,0:512] bf16
  gather_norm_kernel<<<N_, 128, 0, stream>>>(base, idx, abig);
  // 4. GEMM1: pre-BN h (bf16) -> Abig[:,512:1024] + fused BN partial stats
  {
    dim3 grid(MTILES, H_ / 128);
    gemm_mfma_kernel<0><<<grid, 256, 0, stream>>>(abig, KBIG, w0b, D_, b0,
                                                  abig + H_, KBIG, D_,
                                                  psum, psq, nullptr);
  }
  // 5. BN stats reduce -> sc/sh
  bn_stats2_kernel<<<16, 256, 0, stream>>>(psum, psq, gamma, beta, scsh);
  // 6. BN apply + ReLU in place (bf16)
  bn_apply_kernel<<<(N_ * 64) / 256, 256, 0, stream>>>(abig, scsh);
  // 7. fused GEMM2 + per-batch column max (no local materialization)
  {
    dim3 grid(MTILES, E_ / 128);
    gemm_mfma_kernel<1><<<grid, 256, 0, stream>>>(abig, KBIG, wbig, KBIG, biasbig,
                                                  nullptr, 0, KBIG, nullptr, nullptr,
                                                  outenc);
  }
  // 8. decode -> out
  decode_kernel<<<(B_ * E_) / 256, 256, 0, stream>>>(outenc, out);
}